// Round 14
// baseline (320.733 us; speedup 1.0000x reference)
//
#include <hip/hip_runtime.h>
#include <math.h>

#define N_NODES 100000
#define N_EDGES 1600000
#define IN_DIM 64
#define HID 128
#define OUT_DIM 2
#define N_GRAPHS 64

#define NBUK ((N_NODES + 255) / 256)         // 391 buckets of 256 nodes
#define BCAP 4608                            // slots per bucket (mean 4096, 8 sigma)
#define E4 (N_EDGES / 4)                     // 400000 int4 edge groups
#define NBLK_P1 ((E4 + 1023) / 1024)         // 391

#define PCHUNK 256                           // pool rows per block
#define MAXCH 8                              // max chunks per graph

typedef unsigned int uint32;
typedef __attribute__((ext_vector_type(8))) short bf16x8;
typedef __attribute__((ext_vector_type(4))) float f32x4;

static __device__ __forceinline__ ushort f2bf(float f) {
    uint32 u = __float_as_uint(f);
    uint32 r = (u + 0x7fff + ((u >> 16) & 1)) >> 16;  // RNE
    return (ushort)r;
}
static __device__ __forceinline__ float bf2f(uint32 u) {
    return __uint_as_float(u << 16);
}
static __device__ __forceinline__ float bflo(uint32 u) { return bf2f(u & 0xffffu); }
static __device__ __forceinline__ float bfhi(uint32 u) { return bf2f(u >> 16); }
static __device__ __forceinline__ uint32 pack2(float a, float b) {
    return (uint32)f2bf(a) | ((uint32)f2bf(b) << 16);
}

// ---------------- bucketed CSR build ----------------
// gcur holds per-bucket COUNTS (memset 0). Edge packed: (dst&255)<<24 | src.
__global__ __launch_bounds__(1024) void k_pass1(const int4* __restrict__ src4,
                                                const int4* __restrict__ dst4,
                                                int* __restrict__ gcur,
                                                int* __restrict__ bpak) {
    __shared__ int hist[NBUK];
    __shared__ int base[NBUK];
    int tid = threadIdx.x;
    if (tid < NBUK) hist[tid] = 0;
    __syncthreads();
    int i4 = blockIdx.x * 1024 + tid;
    bool act = i4 < E4;
    int4 d = {0, 0, 0, 0}, s = {0, 0, 0, 0};
    if (act) {
        d = dst4[i4];
        s = src4[i4];
        atomicAdd(&hist[d.x >> 8], 1);
        atomicAdd(&hist[d.y >> 8], 1);
        atomicAdd(&hist[d.z >> 8], 1);
        atomicAdd(&hist[d.w >> 8], 1);
    }
    __syncthreads();
    if (tid < NBUK) {
        int c = hist[tid];
        base[tid] = tid * BCAP + (c ? atomicAdd(&gcur[tid], c) : 0);
        hist[tid] = 0;
    }
    __syncthreads();
    if (act) {
        int b0 = d.x >> 8, r0 = atomicAdd(&hist[b0], 1);
        int b1 = d.y >> 8, r1 = atomicAdd(&hist[b1], 1);
        int b2 = d.z >> 8, r2 = atomicAdd(&hist[b2], 1);
        int b3 = d.w >> 8, r3 = atomicAdd(&hist[b3], 1);
        bpak[base[b0] + r0] = ((d.x & 255) << 24) | s.x;
        bpak[base[b1] + r1] = ((d.y & 255) << 24) | s.y;
        bpak[base[b2] + r2] = ((d.z & 255) << 24) | s.z;
        bpak[base[b3] + r3] = ((d.w & 255) << 24) | s.w;
    }
}

// pass 2: per-bucket counting sort + fused xscale; bstart computed in-block from gcur.
__global__ __launch_bounds__(1024) void k_pass2(const int* __restrict__ gcur,
                                                const int* __restrict__ bpak,
                                                const float* __restrict__ x,
                                                int* __restrict__ row_start,
                                                float* __restrict__ dinv,
                                                int* __restrict__ csr,
                                                ushort* __restrict__ xs) {
    __shared__ int cnt[256];
    __shared__ int sc[256];
    __shared__ int lst[256];
    __shared__ float sdinv[256];
    __shared__ int sg[1024];
    __shared__ int sgb;
    int b = blockIdx.x;
    int tid = threadIdx.x;
    int node0 = b * 256;
    int nloc = N_NODES - node0;
    if (nloc > 256) nloc = 256;
    int bbase = b * BCAP;
    int Eb = gcur[b];

    // exclusive prefix over bucket counts -> global base gb
    sg[tid] = (tid < NBUK) ? gcur[tid] : 0;
    if (tid < 256) cnt[tid] = 0;
    __syncthreads();
    for (int off = 1; off < 512; off <<= 1) {
        int u = (tid >= off) ? sg[tid - off] : 0;
        __syncthreads();
        sg[tid] += u;
        __syncthreads();
    }
    if (tid == 0) sgb = (b == 0) ? 0 : sg[b - 1];
    __syncthreads();
    int gb = sgb;

    for (int i = tid; i < Eb; i += 1024) atomicAdd(&cnt[(uint32)bpak[bbase + i] >> 24], 1);
    __syncthreads();
    int v = 0;
    if (tid < 256) {
        v = cnt[tid];
        sc[tid] = v;
    }
    __syncthreads();
    for (int off = 1; off < 256; off <<= 1) {
        int u = 0;
        if (tid < 256 && tid >= off) u = sc[tid - off];
        __syncthreads();
        if (tid < 256) sc[tid] += u;
        __syncthreads();
    }
    if (tid < 256) {
        int excl = sc[tid] - v;
        lst[tid] = excl;
        if (tid < nloc) {
            float dv = rsqrtf((float)(v + 1));  // +1 self loop
            row_start[node0 + tid] = gb + excl;
            dinv[node0 + tid] = dv;
            sdinv[tid] = dv;
        }
        cnt[tid] = 0;
    }
    __syncthreads();
    for (int i = tid; i < Eb; i += 1024) {
        int p = bpak[bbase + i];
        int dl = (uint32)p >> 24;
        int r = atomicAdd(&cnt[dl], 1);
        csr[gb + lst[dl] + r] = p & 0xFFFFFF;
    }
    // fused xscale for this block's 256 nodes
    int f0 = node0 * 16;
    int f1 = (node0 + nloc) * 16;
    for (int idx = f0 + tid; idx < f1; idx += 1024) {
        float dv = sdinv[(idx >> 4) - node0];
        float4 vv = ((const float4*)x)[idx];
        ushort4 o;
        o.x = f2bf(vv.x * dv);
        o.y = f2bf(vv.y * dv);
        o.z = f2bf(vv.z * dv);
        o.w = f2bf(vv.w * dv);
        ((ushort4*)xs)[idx] = o;
    }
}

// ---------------- graph boundaries from sorted batch ----------------
__global__ __launch_bounds__(256) void k_gbound(const int* __restrict__ batch,
                                                int* __restrict__ gstart,
                                                int* __restrict__ row_start) {
    int n = blockIdx.x * 256 + threadIdx.x;
    if (n >= N_NODES) return;
    if (n == 0) {
        for (int g = 0; g <= batch[0]; ++g) gstart[g] = 0;
    } else {
        int a = batch[n - 1], b = batch[n];
        for (int g = a + 1; g <= b; ++g) gstart[g] = n;
    }
    if (n == N_NODES - 1) {
        for (int g = batch[n] + 1; g <= N_GRAPHS; ++g) gstart[g] = N_NODES;
        row_start[N_NODES] = N_EDGES;
    }
}

// ---------------- layer-1 aggregation (row-major xs, 32 lanes/node) ----------------
__global__ __launch_bounds__(256) void k_agg1(const int* __restrict__ row_start,
                                              const int* __restrict__ csr,
                                              const uint32* __restrict__ xs,
                                              const float* __restrict__ dinv,
                                              uint32* __restrict__ outb) {
    int d = blockIdx.x * 8 + (threadIdx.x >> 5);
    int l = threadIdx.x & 31;
    float dd = dinv[d];
    uint32 u = xs[(long long)d * 32 + l];
    float a0 = bflo(u), a1 = bfhi(u);
    int e = row_start[d];
    int eend = row_start[d + 1];
    for (; e + 7 < eend; e += 8) {
        int s0 = csr[e], s1 = csr[e + 1], s2 = csr[e + 2], s3 = csr[e + 3];
        int s4 = csr[e + 4], s5 = csr[e + 5], s6 = csr[e + 6], s7 = csr[e + 7];
        uint32 w0 = xs[(long long)s0 * 32 + l];
        uint32 w1 = xs[(long long)s1 * 32 + l];
        uint32 w2 = xs[(long long)s2 * 32 + l];
        uint32 w3 = xs[(long long)s3 * 32 + l];
        uint32 w4 = xs[(long long)s4 * 32 + l];
        uint32 w5 = xs[(long long)s5 * 32 + l];
        uint32 w6 = xs[(long long)s6 * 32 + l];
        uint32 w7 = xs[(long long)s7 * 32 + l];
        a0 += ((bflo(w0) + bflo(w1)) + (bflo(w2) + bflo(w3))) +
              ((bflo(w4) + bflo(w5)) + (bflo(w6) + bflo(w7)));
        a1 += ((bfhi(w0) + bfhi(w1)) + (bfhi(w2) + bfhi(w3))) +
              ((bfhi(w4) + bfhi(w5)) + (bfhi(w6) + bfhi(w7)));
    }
    for (; e + 3 < eend; e += 4) {
        int s0 = csr[e], s1 = csr[e + 1], s2 = csr[e + 2], s3 = csr[e + 3];
        uint32 w0 = xs[(long long)s0 * 32 + l];
        uint32 w1 = xs[(long long)s1 * 32 + l];
        uint32 w2 = xs[(long long)s2 * 32 + l];
        uint32 w3 = xs[(long long)s3 * 32 + l];
        a0 += (bflo(w0) + bflo(w1)) + (bflo(w2) + bflo(w3));
        a1 += (bfhi(w0) + bfhi(w1)) + (bfhi(w2) + bfhi(w3));
    }
    for (; e < eend; ++e) {
        uint32 w = xs[(long long)csr[e] * 32 + l];
        a0 += bflo(w);
        a1 += bfhi(w);
    }
    outb[(long long)d * 32 + l] = (uint32)f2bf(a0 * dd) | ((uint32)f2bf(a1 * dd) << 16);
}

// ---------------- layer-2 aggregation: XCD-sliced ----------------
// hs stored slice-major [8][N][8 uint32]; block's slice = blockIdx&7 -> same XCD
// (round-robin dispatch) -> 3.2 MB slice stays L2-resident. 8 lanes per node.
__global__ __launch_bounds__(256) void k_agg2(const int* __restrict__ row_start,
                                              const int* __restrict__ csr,
                                              const uint32* __restrict__ hsl,
                                              const float* __restrict__ dinv,
                                              uint32* __restrict__ outb) {
    int s = blockIdx.x & 7;
    int nb = blockIdx.x >> 3;
    int grp = threadIdx.x >> 3;  // 0..31, one node each
    int j = threadIdx.x & 7;
    int d = nb * 32 + grp;
    const uint32* tb = hsl + (long long)s * (N_NODES * 8);
    float dd = dinv[d];
    uint32 u = tb[d * 8 + j];
    float a0 = bflo(u), a1 = bfhi(u);
    int e = row_start[d];
    int eend = row_start[d + 1];
    for (; e + 7 < eend; e += 8) {
        int s0 = __builtin_nontemporal_load(csr + e);
        int s1 = __builtin_nontemporal_load(csr + e + 1);
        int s2 = __builtin_nontemporal_load(csr + e + 2);
        int s3 = __builtin_nontemporal_load(csr + e + 3);
        int s4 = __builtin_nontemporal_load(csr + e + 4);
        int s5 = __builtin_nontemporal_load(csr + e + 5);
        int s6 = __builtin_nontemporal_load(csr + e + 6);
        int s7 = __builtin_nontemporal_load(csr + e + 7);
        uint32 w0 = tb[s0 * 8 + j];
        uint32 w1 = tb[s1 * 8 + j];
        uint32 w2 = tb[s2 * 8 + j];
        uint32 w3 = tb[s3 * 8 + j];
        uint32 w4 = tb[s4 * 8 + j];
        uint32 w5 = tb[s5 * 8 + j];
        uint32 w6 = tb[s6 * 8 + j];
        uint32 w7 = tb[s7 * 8 + j];
        a0 += ((bflo(w0) + bflo(w1)) + (bflo(w2) + bflo(w3))) +
              ((bflo(w4) + bflo(w5)) + (bflo(w6) + bflo(w7)));
        a1 += ((bfhi(w0) + bfhi(w1)) + (bfhi(w2) + bfhi(w3))) +
              ((bfhi(w4) + bfhi(w5)) + (bfhi(w6) + bfhi(w7)));
    }
    for (; e < eend; ++e) {
        int s0 = __builtin_nontemporal_load(csr + e);
        uint32 w = tb[s0 * 8 + j];
        a0 += bflo(w);
        a1 += bfhi(w);
    }
    __builtin_nontemporal_store(pack2(a0 * dd, a1 * dd), &outb[(long long)d * 64 + s * 8 + j]);
}

// ---------------- MFMA GEMM: out = relu(A[N,K](bf16) @ W[K,128] + b) ----------------
// OUTM: 1 = bf16*dinv, SLICE-MAJOR [8][N][16] out (for sliced agg2); 2 = bf16 row-major
template <int K, int OUTM>
__global__ __launch_bounds__(256) void k_gemm_mfma(const ushort* __restrict__ A,
                                                   const float* __restrict__ W,
                                                   const float* __restrict__ bias,
                                                   const float* __restrict__ dinv,
                                                   ushort* __restrict__ outb) {
    constexpr int KSTEPS = K / 32;
    constexpr int LDSK = K + 8;          // pad: col stride 4 banks -> 2-way (free)
    __shared__ ushort WT[128 * LDSK];    // [col][k] bf16
    int tid = threadIdx.x;
    for (int idx = tid; idx < K * 128; idx += 256) {
        int k = idx >> 7, c = idx & 127;
        WT[c * LDSK + k] = f2bf(W[idx]);
    }
    __syncthreads();

    int w = tid >> 6, l = tid & 63;
    int row0 = blockIdx.x * 64 + w * 16;
    int arow = row0 + (l & 15);
    if (arow > N_NODES - 1) arow = N_NODES - 1;
    int koff = (l >> 4) * 8;

    bf16x8 af[KSTEPS];
#pragma unroll
    for (int ks = 0; ks < KSTEPS; ++ks)
        af[ks] = *(const bf16x8*)(A + (long long)arow * K + ks * 32 + koff);

    f32x4 acc[8];
#pragma unroll
    for (int t = 0; t < 8; ++t) acc[t] = (f32x4){0.f, 0.f, 0.f, 0.f};

#pragma unroll
    for (int ks = 0; ks < KSTEPS; ++ks) {
#pragma unroll
        for (int t = 0; t < 8; ++t) {
            int c = t * 16 + (l & 15);
            bf16x8 bf = *(const bf16x8*)&WT[c * LDSK + ks * 32 + koff];
            acc[t] = __builtin_amdgcn_mfma_f32_16x16x32_bf16(af[ks], bf, acc[t], 0, 0, 0);
        }
    }

    int rbase = row0 + ((l >> 4) << 2);
#pragma unroll
    for (int t = 0; t < 8; ++t) {
        int col = t * 16 + (l & 15);
        float bb = bias[col];
#pragma unroll
        for (int i = 0; i < 4; ++i) {
            int row = rbase + i;
            if (row < N_NODES) {
                float v = acc[t][i] + bb;
                v = v > 0.f ? v : 0.f;
                if (OUTM == 1) {
                    // slice-major: slice t, within-slice col = l&15
                    outb[(long long)t * (N_NODES * 16) + (long long)row * 16 + (l & 15)] =
                        f2bf(v * dinv[row]);
                } else {
                    outb[(long long)row * HID + col] = f2bf(v);
                }
            }
        }
    }
}

// ---------------- pooling (bf16 input): one block per (graph, chunk) ----------------
__global__ __launch_bounds__(256) void k_pool(const uint32* __restrict__ h2,
                                              const int* __restrict__ gstart,
                                              float* __restrict__ pooled) {
    int g = blockIdx.x >> 3;   // / MAXCH
    int c = blockIdx.x & (MAXCH - 1);
    int r0 = gstart[g] + c * PCHUNK;
    int r1 = gstart[g + 1];
    if (r0 >= r1) return;
    int rend = r0 + PCHUNK;
    if (rend > r1) rend = r1;
    int j = threadIdx.x & 63;   // col pair
    int q = threadIdx.x >> 6;   // 0..3
    float a0 = 0.f, a1 = 0.f, b0 = 0.f, b1 = 0.f;
    int r = r0 + q;
    for (; r + 4 < rend; r += 8) {
        uint32 u = h2[(long long)r * 64 + j];
        uint32 v = h2[(long long)(r + 4) * 64 + j];
        a0 += bflo(u);
        a1 += bfhi(u);
        b0 += bflo(v);
        b1 += bfhi(v);
    }
    for (; r < rend; r += 4) {
        uint32 u = h2[(long long)r * 64 + j];
        a0 += bflo(u);
        a1 += bfhi(u);
    }
    __shared__ float red[256][2];
    red[threadIdx.x][0] = a0 + b0;
    red[threadIdx.x][1] = a1 + b1;
    __syncthreads();
    if (q == 0) {
        float s0 = (red[j][0] + red[j + 64][0]) + (red[j + 128][0] + red[j + 192][0]);
        float s1 = (red[j][1] + red[j + 64][1]) + (red[j + 128][1] + red[j + 192][1]);
        atomicAdd(&pooled[g * HID + 2 * j], s0);
        atomicAdd(&pooled[g * HID + 2 * j + 1], s1);
    }
}

// ---------------- head: 4 lanes per graph ----------------
__global__ __launch_bounds__(256) void k_head(const float* __restrict__ pooled,
                                              const int* __restrict__ gstart,
                                              const float* __restrict__ Wfc,
                                              const float* __restrict__ bfc,
                                              float* __restrict__ out) {
    int t = threadIdx.x;
    int g = t >> 2, sub = t & 3;
    float inv = 1.0f / fmaxf((float)(gstart[g + 1] - gstart[g]), 1.0f);
    float l0 = 0.f, l1 = 0.f;
    for (int j = sub * 32; j < sub * 32 + 32; ++j) {
        float p = pooled[g * HID + j] * inv;
        l0 += p * Wfc[j * OUT_DIM + 0];
        l1 += p * Wfc[j * OUT_DIM + 1];
    }
    l0 += __shfl_xor(l0, 1);
    l1 += __shfl_xor(l1, 1);
    l0 += __shfl_xor(l0, 2);
    l1 += __shfl_xor(l1, 2);
    if (sub == 0) {
        l0 += bfc[0];
        l1 += bfc[1];
        float m = fmaxf(l0, l1);
        float lse = m + logf(expf(l0 - m) + expf(l1 - m));
        out[g * OUT_DIM + 0] = l0 - lse;
        out[g * OUT_DIM + 1] = l1 - lse;
    }
}

extern "C" void kernel_launch(void* const* d_in, const int* in_sizes, int n_in,
                              void* d_out, int out_size, void* d_ws, size_t ws_size,
                              hipStream_t stream) {
    const float* x   = (const float*)d_in[0];
    const float* W1  = (const float*)d_in[1];
    const float* b1  = (const float*)d_in[2];
    const float* W2  = (const float*)d_in[3];
    const float* b2  = (const float*)d_in[4];
    const float* Wfc = (const float*)d_in[5];
    const float* bfc = (const float*)d_in[6];
    const int* ei    = (const int*)d_in[7];   // [2, E]
    const int* batch = (const int*)d_in[8];
    const int* src = ei;
    const int* dst = ei + N_EDGES;
    float* out = (float*)d_out;

    // workspace layout
    float* bufA = (float*)d_ws;                    // bpak overlay, then agg outputs (bf16)
    float* bufB = bufA + (long long)N_NODES * HID; // xs / hs / h2 (bf16)
    int* bpak = (int*)bufA;                        // NBUK*BCAP packed edges (dead before agg1)
    ushort* agg1o = (ushort*)bufA;                 // N*64 bf16
    ushort* agg2o = (ushort*)bufA;                 // N*128 bf16
    ushort* xs = (ushort*)bufB;                    // N*64 bf16
    ushort* hs = (ushort*)bufB;                    // [8][N][16] bf16 slice-major
    ushort* h2 = (ushort*)bufB;                    // N*128 bf16 (overwrites hs after agg2)
    int* row_start = (int*)(bufB + (long long)N_NODES * HID);  // N+1
    float* dinv = (float*)(row_start + N_NODES + 1);  // N
    int* gcur = (int*)(dinv + N_NODES);            // NBUK
    int* gstart = gcur + NBUK;                     // N_GRAPHS+1
    int* csr = gstart + (N_GRAPHS + 1);            // E
    float* pooled = (float*)(csr + N_EDGES);       // G*HID

    // ----- CSR build -----
    hipMemsetAsync(gcur, 0, NBUK * sizeof(int), stream);
    hipMemsetAsync(pooled, 0, N_GRAPHS * HID * sizeof(float), stream);
    k_pass1<<<NBLK_P1, 1024, 0, stream>>>((const int4*)src, (const int4*)dst, gcur, bpak);
    k_pass2<<<NBUK, 1024, 0, stream>>>(gcur, bpak, x, row_start, dinv, csr, xs);
    k_gbound<<<(N_NODES + 255) / 256, 256, 0, stream>>>(batch, gstart, row_start);

    const int NGBLK = (N_NODES + 63) / 64;

    // ----- layer 1 -----
    k_agg1<<<N_NODES / 8, 256, 0, stream>>>(row_start, csr, (const uint32*)xs, dinv,
                                            (uint32*)agg1o);
    k_gemm_mfma<IN_DIM, 1><<<NGBLK, 256, 0, stream>>>(agg1o, W1, b1, dinv, hs);

    // ----- layer 2 (XCD-sliced gather over slice-major hs) -----
    k_agg2<<<(N_NODES / 32) * 8, 256, 0, stream>>>(row_start, csr, (const uint32*)hs, dinv,
                                                   (uint32*)agg2o);
    k_gemm_mfma<HID, 2><<<NGBLK, 256, 0, stream>>>(agg2o, W2, b2, dinv, h2);

    // ----- pool + head -----
    k_pool<<<N_GRAPHS * MAXCH, 256, 0, stream>>>((const uint32*)h2, gstart, pooled);
    k_head<<<1, 256, 0, stream>>>(pooled, gstart, Wfc, bfc, out);
}

// Round 15
// 212.256 us; speedup vs baseline: 1.5111x; 1.5111x over previous
//
#include <hip/hip_runtime.h>
#include <math.h>

#define N_NODES 100000
#define N_EDGES 1600000
#define IN_DIM 64
#define HID 128
#define OUT_DIM 2
#define N_GRAPHS 64

#define NBUK ((N_NODES + 255) / 256)         // 391 buckets of 256 nodes
#define BCAP 4608                            // slots per bucket (mean 4096, 8 sigma)
#define E4 (N_EDGES / 4)                     // 400000 int4 edge groups
#define NBLK_P1 ((E4 + 1023) / 1024)         // 391

#define PCHUNK 256                           // pool rows per block
#define MAXCH 8                              // max chunks per graph

typedef unsigned int uint32;
typedef __attribute__((ext_vector_type(8))) short bf16x8;
typedef __attribute__((ext_vector_type(4))) float f32x4;

static __device__ __forceinline__ ushort f2bf(float f) {
    uint32 u = __float_as_uint(f);
    uint32 r = (u + 0x7fff + ((u >> 16) & 1)) >> 16;  // RNE
    return (ushort)r;
}
static __device__ __forceinline__ float bf2f(uint32 u) {
    return __uint_as_float(u << 16);
}
static __device__ __forceinline__ float bflo(uint32 u) { return bf2f(u & 0xffffu); }
static __device__ __forceinline__ float bfhi(uint32 u) { return bf2f(u >> 16); }

// ---------------- bucketed CSR build ----------------
// gcur holds per-bucket COUNTS (memset 0). Edge packed: (dst&255)<<24 | src.
__global__ __launch_bounds__(1024) void k_pass1(const int4* __restrict__ src4,
                                                const int4* __restrict__ dst4,
                                                int* __restrict__ gcur,
                                                int* __restrict__ bpak) {
    __shared__ int hist[NBUK];
    __shared__ int base[NBUK];
    int tid = threadIdx.x;
    if (tid < NBUK) hist[tid] = 0;
    __syncthreads();
    int i4 = blockIdx.x * 1024 + tid;
    bool act = i4 < E4;
    int4 d = {0, 0, 0, 0}, s = {0, 0, 0, 0};
    if (act) {
        d = dst4[i4];
        s = src4[i4];
        atomicAdd(&hist[d.x >> 8], 1);
        atomicAdd(&hist[d.y >> 8], 1);
        atomicAdd(&hist[d.z >> 8], 1);
        atomicAdd(&hist[d.w >> 8], 1);
    }
    __syncthreads();
    if (tid < NBUK) {
        int c = hist[tid];
        base[tid] = tid * BCAP + (c ? atomicAdd(&gcur[tid], c) : 0);
        hist[tid] = 0;
    }
    __syncthreads();
    if (act) {
        int b0 = d.x >> 8, r0 = atomicAdd(&hist[b0], 1);
        int b1 = d.y >> 8, r1 = atomicAdd(&hist[b1], 1);
        int b2 = d.z >> 8, r2 = atomicAdd(&hist[b2], 1);
        int b3 = d.w >> 8, r3 = atomicAdd(&hist[b3], 1);
        bpak[base[b0] + r0] = ((d.x & 255) << 24) | s.x;
        bpak[base[b1] + r1] = ((d.y & 255) << 24) | s.y;
        bpak[base[b2] + r2] = ((d.z & 255) << 24) | s.z;
        bpak[base[b3] + r3] = ((d.w & 255) << 24) | s.w;
    }
}

// pass 2: per-bucket counting sort + fused xscale + fused graph-boundary detection.
__global__ __launch_bounds__(1024) void k_pass2(const int* __restrict__ gcur,
                                                const int* __restrict__ bpak,
                                                const float* __restrict__ x,
                                                const int* __restrict__ batch,
                                                int* __restrict__ row_start,
                                                float* __restrict__ dinv,
                                                int* __restrict__ csr,
                                                ushort* __restrict__ xs,
                                                int* __restrict__ gstart) {
    __shared__ int cnt[256];
    __shared__ int sc[256];
    __shared__ int lst[256];
    __shared__ float sdinv[256];
    __shared__ int sg[1024];
    __shared__ int sgb;
    int b = blockIdx.x;
    int tid = threadIdx.x;
    int node0 = b * 256;
    int nloc = N_NODES - node0;
    if (nloc > 256) nloc = 256;
    int bbase = b * BCAP;
    int Eb = gcur[b];

    // exclusive prefix over bucket counts -> global base gb
    sg[tid] = (tid < NBUK) ? gcur[tid] : 0;
    if (tid < 256) cnt[tid] = 0;
    __syncthreads();
    for (int off = 1; off < 512; off <<= 1) {
        int u = (tid >= off) ? sg[tid - off] : 0;
        __syncthreads();
        sg[tid] += u;
        __syncthreads();
    }
    if (tid == 0) sgb = (b == 0) ? 0 : sg[b - 1];
    __syncthreads();
    int gb = sgb;

    for (int i = tid; i < Eb; i += 1024) atomicAdd(&cnt[(uint32)bpak[bbase + i] >> 24], 1);
    __syncthreads();
    int v = 0;
    if (tid < 256) {
        v = cnt[tid];
        sc[tid] = v;
    }
    __syncthreads();
    for (int off = 1; off < 256; off <<= 1) {
        int u = 0;
        if (tid < 256 && tid >= off) u = sc[tid - off];
        __syncthreads();
        if (tid < 256) sc[tid] += u;
        __syncthreads();
    }
    if (tid < 256) {
        int excl = sc[tid] - v;
        lst[tid] = excl;
        if (tid < nloc) {
            int n = node0 + tid;
            float dv = rsqrtf((float)(v + 1));  // +1 self loop
            row_start[n] = gb + excl;
            dinv[n] = dv;
            sdinv[tid] = dv;
            // fused graph-boundary detection (batch sorted)
            if (n == 0) {
                for (int g = 0; g <= batch[0]; ++g) gstart[g] = 0;
            } else {
                int a = batch[n - 1], bb = batch[n];
                for (int g = a + 1; g <= bb; ++g) gstart[g] = n;
            }
            if (n == N_NODES - 1) {
                for (int g = batch[n] + 1; g <= N_GRAPHS; ++g) gstart[g] = N_NODES;
                row_start[N_NODES] = N_EDGES;
            }
        }
        cnt[tid] = 0;
    }
    __syncthreads();
    for (int i = tid; i < Eb; i += 1024) {
        int p = bpak[bbase + i];
        int dl = (uint32)p >> 24;
        int r = atomicAdd(&cnt[dl], 1);
        csr[gb + lst[dl] + r] = p & 0xFFFFFF;
    }
    // fused xscale for this block's 256 nodes
    int f0 = node0 * 16;
    int f1 = (node0 + nloc) * 16;
    for (int idx = f0 + tid; idx < f1; idx += 1024) {
        float dv = sdinv[(idx >> 4) - node0];
        float4 vv = ((const float4*)x)[idx];
        ushort4 o;
        o.x = f2bf(vv.x * dv);
        o.y = f2bf(vv.y * dv);
        o.z = f2bf(vv.z * dv);
        o.w = f2bf(vv.w * dv);
        ((ushort4*)xs)[idx] = o;
    }
}

// ---------------- aggregation (gather, CSR, bf16 in AND out, 8-deep MLP) ----------------
__global__ __launch_bounds__(256) void k_agg1(const int* __restrict__ row_start,
                                              const int* __restrict__ csr,
                                              const uint32* __restrict__ xs,
                                              const float* __restrict__ dinv,
                                              uint32* __restrict__ outb) {
    int d = blockIdx.x * 8 + (threadIdx.x >> 5);
    int l = threadIdx.x & 31;
    float dd = dinv[d];
    uint32 u = xs[(long long)d * 32 + l];
    float a0 = bflo(u), a1 = bfhi(u);
    int e = row_start[d];
    int eend = row_start[d + 1];
    for (; e + 7 < eend; e += 8) {
        int s0 = csr[e], s1 = csr[e + 1], s2 = csr[e + 2], s3 = csr[e + 3];
        int s4 = csr[e + 4], s5 = csr[e + 5], s6 = csr[e + 6], s7 = csr[e + 7];
        uint32 w0 = xs[(long long)s0 * 32 + l];
        uint32 w1 = xs[(long long)s1 * 32 + l];
        uint32 w2 = xs[(long long)s2 * 32 + l];
        uint32 w3 = xs[(long long)s3 * 32 + l];
        uint32 w4 = xs[(long long)s4 * 32 + l];
        uint32 w5 = xs[(long long)s5 * 32 + l];
        uint32 w6 = xs[(long long)s6 * 32 + l];
        uint32 w7 = xs[(long long)s7 * 32 + l];
        a0 += ((bflo(w0) + bflo(w1)) + (bflo(w2) + bflo(w3))) +
              ((bflo(w4) + bflo(w5)) + (bflo(w6) + bflo(w7)));
        a1 += ((bfhi(w0) + bfhi(w1)) + (bfhi(w2) + bfhi(w3))) +
              ((bfhi(w4) + bfhi(w5)) + (bfhi(w6) + bfhi(w7)));
    }
    for (; e + 3 < eend; e += 4) {
        int s0 = csr[e], s1 = csr[e + 1], s2 = csr[e + 2], s3 = csr[e + 3];
        uint32 w0 = xs[(long long)s0 * 32 + l];
        uint32 w1 = xs[(long long)s1 * 32 + l];
        uint32 w2 = xs[(long long)s2 * 32 + l];
        uint32 w3 = xs[(long long)s3 * 32 + l];
        a0 += (bflo(w0) + bflo(w1)) + (bflo(w2) + bflo(w3));
        a1 += (bfhi(w0) + bfhi(w1)) + (bfhi(w2) + bfhi(w3));
    }
    for (; e < eend; ++e) {
        uint32 w = xs[(long long)csr[e] * 32 + l];
        a0 += bflo(w);
        a1 += bfhi(w);
    }
    outb[(long long)d * 32 + l] = (uint32)f2bf(a0 * dd) | ((uint32)f2bf(a1 * dd) << 16);
}

__global__ __launch_bounds__(256) void k_agg2(const int* __restrict__ row_start,
                                              const int* __restrict__ csr,
                                              const uint2* __restrict__ hs,
                                              const float* __restrict__ dinv,
                                              uint2* __restrict__ outb) {
    int d = blockIdx.x * 8 + (threadIdx.x >> 5);
    int l = threadIdx.x & 31;
    float dd = dinv[d];
    uint2 u = hs[(long long)d * 32 + l];
    float a0 = bflo(u.x), a1 = bfhi(u.x), a2 = bflo(u.y), a3 = bfhi(u.y);
    int e = row_start[d];
    int eend = row_start[d + 1];
    for (; e + 7 < eend; e += 8) {
        int s0 = csr[e], s1 = csr[e + 1], s2 = csr[e + 2], s3 = csr[e + 3];
        int s4 = csr[e + 4], s5 = csr[e + 5], s6 = csr[e + 6], s7 = csr[e + 7];
        uint2 w0 = hs[(long long)s0 * 32 + l];
        uint2 w1 = hs[(long long)s1 * 32 + l];
        uint2 w2 = hs[(long long)s2 * 32 + l];
        uint2 w3 = hs[(long long)s3 * 32 + l];
        uint2 w4 = hs[(long long)s4 * 32 + l];
        uint2 w5 = hs[(long long)s5 * 32 + l];
        uint2 w6 = hs[(long long)s6 * 32 + l];
        uint2 w7 = hs[(long long)s7 * 32 + l];
        a0 += ((bflo(w0.x) + bflo(w1.x)) + (bflo(w2.x) + bflo(w3.x))) +
              ((bflo(w4.x) + bflo(w5.x)) + (bflo(w6.x) + bflo(w7.x)));
        a1 += ((bfhi(w0.x) + bfhi(w1.x)) + (bfhi(w2.x) + bfhi(w3.x))) +
              ((bfhi(w4.x) + bfhi(w5.x)) + (bfhi(w6.x) + bfhi(w7.x)));
        a2 += ((bflo(w0.y) + bflo(w1.y)) + (bflo(w2.y) + bflo(w3.y))) +
              ((bflo(w4.y) + bflo(w5.y)) + (bflo(w6.y) + bflo(w7.y)));
        a3 += ((bfhi(w0.y) + bfhi(w1.y)) + (bfhi(w2.y) + bfhi(w3.y))) +
              ((bfhi(w4.y) + bfhi(w5.y)) + (bfhi(w6.y) + bfhi(w7.y)));
    }
    for (; e + 3 < eend; e += 4) {
        int s0 = csr[e], s1 = csr[e + 1], s2 = csr[e + 2], s3 = csr[e + 3];
        uint2 w0 = hs[(long long)s0 * 32 + l];
        uint2 w1 = hs[(long long)s1 * 32 + l];
        uint2 w2 = hs[(long long)s2 * 32 + l];
        uint2 w3 = hs[(long long)s3 * 32 + l];
        a0 += (bflo(w0.x) + bflo(w1.x)) + (bflo(w2.x) + bflo(w3.x));
        a1 += (bfhi(w0.x) + bfhi(w1.x)) + (bfhi(w2.x) + bfhi(w3.x));
        a2 += (bflo(w0.y) + bflo(w1.y)) + (bflo(w2.y) + bflo(w3.y));
        a3 += (bfhi(w0.y) + bfhi(w1.y)) + (bfhi(w2.y) + bfhi(w3.y));
    }
    for (; e < eend; ++e) {
        uint2 w = hs[(long long)csr[e] * 32 + l];
        a0 += bflo(w.x);
        a1 += bfhi(w.x);
        a2 += bflo(w.y);
        a3 += bfhi(w.y);
    }
    uint2 o;
    o.x = (uint32)f2bf(a0 * dd) | ((uint32)f2bf(a1 * dd) << 16);
    o.y = (uint32)f2bf(a2 * dd) | ((uint32)f2bf(a3 * dd) << 16);
    outb[(long long)d * 32 + l] = o;
}

// ---------------- MFMA GEMM: out[N,128] = relu(A[N,K](bf16) @ W[K,128] + b) ----------------
// OUTM: 1 = bf16 * dinv[row], 2 = bf16
template <int K, int OUTM>
__global__ __launch_bounds__(256) void k_gemm_mfma(const ushort* __restrict__ A,
                                                   const float* __restrict__ W,
                                                   const float* __restrict__ bias,
                                                   const float* __restrict__ dinv,
                                                   ushort* __restrict__ outb) {
    constexpr int KSTEPS = K / 32;
    constexpr int LDSK = K + 8;          // pad: col stride 4 banks -> 2-way (free)
    __shared__ ushort WT[128 * LDSK];    // [col][k] bf16
    int tid = threadIdx.x;
    for (int idx = tid; idx < K * 128; idx += 256) {
        int k = idx >> 7, c = idx & 127;
        WT[c * LDSK + k] = f2bf(W[idx]);
    }
    __syncthreads();

    int w = tid >> 6, l = tid & 63;
    int row0 = blockIdx.x * 64 + w * 16;
    int arow = row0 + (l & 15);
    if (arow > N_NODES - 1) arow = N_NODES - 1;
    int koff = (l >> 4) * 8;

    bf16x8 af[KSTEPS];
#pragma unroll
    for (int ks = 0; ks < KSTEPS; ++ks)
        af[ks] = *(const bf16x8*)(A + (long long)arow * K + ks * 32 + koff);

    f32x4 acc[8];
#pragma unroll
    for (int t = 0; t < 8; ++t) acc[t] = (f32x4){0.f, 0.f, 0.f, 0.f};

#pragma unroll
    for (int ks = 0; ks < KSTEPS; ++ks) {
#pragma unroll
        for (int t = 0; t < 8; ++t) {
            int c = t * 16 + (l & 15);
            bf16x8 bf = *(const bf16x8*)&WT[c * LDSK + ks * 32 + koff];
            acc[t] = __builtin_amdgcn_mfma_f32_16x16x32_bf16(af[ks], bf, acc[t], 0, 0, 0);
        }
    }

    int rbase = row0 + ((l >> 4) << 2);
#pragma unroll
    for (int t = 0; t < 8; ++t) {
        int col = t * 16 + (l & 15);
        float bb = bias[col];
#pragma unroll
        for (int i = 0; i < 4; ++i) {
            int row = rbase + i;
            if (row < N_NODES) {
                float v = acc[t][i] + bb;
                v = v > 0.f ? v : 0.f;
                if (OUTM == 1) v *= dinv[row];
                outb[(long long)row * HID + col] = f2bf(v);
            }
        }
    }
}

// ---------------- pooling (bf16 input): one block per (graph, chunk) ----------------
__global__ __launch_bounds__(256) void k_pool(const uint32* __restrict__ h2,
                                              const int* __restrict__ gstart,
                                              float* __restrict__ pooled) {
    int g = blockIdx.x >> 3;   // / MAXCH
    int c = blockIdx.x & (MAXCH - 1);
    int r0 = gstart[g] + c * PCHUNK;
    int r1 = gstart[g + 1];
    if (r0 >= r1) return;
    int rend = r0 + PCHUNK;
    if (rend > r1) rend = r1;
    int j = threadIdx.x & 63;   // col pair
    int q = threadIdx.x >> 6;   // 0..3
    float a0 = 0.f, a1 = 0.f, b0 = 0.f, b1 = 0.f;
    int r = r0 + q;
    for (; r + 4 < rend; r += 8) {
        uint32 u = h2[(long long)r * 64 + j];
        uint32 v = h2[(long long)(r + 4) * 64 + j];
        a0 += bflo(u);
        a1 += bfhi(u);
        b0 += bflo(v);
        b1 += bfhi(v);
    }
    for (; r < rend; r += 4) {
        uint32 u = h2[(long long)r * 64 + j];
        a0 += bflo(u);
        a1 += bfhi(u);
    }
    __shared__ float red[256][2];
    red[threadIdx.x][0] = a0 + b0;
    red[threadIdx.x][1] = a1 + b1;
    __syncthreads();
    if (q == 0) {
        float s0 = (red[j][0] + red[j + 64][0]) + (red[j + 128][0] + red[j + 192][0]);
        float s1 = (red[j][1] + red[j + 64][1]) + (red[j + 128][1] + red[j + 192][1]);
        atomicAdd(&pooled[g * HID + 2 * j], s0);
        atomicAdd(&pooled[g * HID + 2 * j + 1], s1);
    }
}

// ---------------- head: 4 lanes per graph ----------------
__global__ __launch_bounds__(256) void k_head(const float* __restrict__ pooled,
                                              const int* __restrict__ gstart,
                                              const float* __restrict__ Wfc,
                                              const float* __restrict__ bfc,
                                              float* __restrict__ out) {
    int t = threadIdx.x;
    int g = t >> 2, sub = t & 3;
    float inv = 1.0f / fmaxf((float)(gstart[g + 1] - gstart[g]), 1.0f);
    float l0 = 0.f, l1 = 0.f;
    for (int j = sub * 32; j < sub * 32 + 32; ++j) {
        float p = pooled[g * HID + j] * inv;
        l0 += p * Wfc[j * OUT_DIM + 0];
        l1 += p * Wfc[j * OUT_DIM + 1];
    }
    l0 += __shfl_xor(l0, 1);
    l1 += __shfl_xor(l1, 1);
    l0 += __shfl_xor(l0, 2);
    l1 += __shfl_xor(l1, 2);
    if (sub == 0) {
        l0 += bfc[0];
        l1 += bfc[1];
        float m = fmaxf(l0, l1);
        float lse = m + logf(expf(l0 - m) + expf(l1 - m));
        out[g * OUT_DIM + 0] = l0 - lse;
        out[g * OUT_DIM + 1] = l1 - lse;
    }
}

extern "C" void kernel_launch(void* const* d_in, const int* in_sizes, int n_in,
                              void* d_out, int out_size, void* d_ws, size_t ws_size,
                              hipStream_t stream) {
    const float* x   = (const float*)d_in[0];
    const float* W1  = (const float*)d_in[1];
    const float* b1  = (const float*)d_in[2];
    const float* W2  = (const float*)d_in[3];
    const float* b2  = (const float*)d_in[4];
    const float* Wfc = (const float*)d_in[5];
    const float* bfc = (const float*)d_in[6];
    const int* ei    = (const int*)d_in[7];   // [2, E]
    const int* batch = (const int*)d_in[8];
    const int* src = ei;
    const int* dst = ei + N_EDGES;
    float* out = (float*)d_out;

    // workspace layout
    float* bufA = (float*)d_ws;                    // bpak overlay, then agg outputs (bf16)
    float* bufB = bufA + (long long)N_NODES * HID; // xs / hs / h2 (bf16)
    int* bpak = (int*)bufA;                        // NBUK*BCAP packed edges (dead before agg1)
    ushort* agg1o = (ushort*)bufA;                 // N*64 bf16
    ushort* agg2o = (ushort*)bufA;                 // N*128 bf16
    ushort* xs = (ushort*)bufB;                    // N*64 bf16
    ushort* hs = (ushort*)bufB;                    // N*128 bf16 (overwrites xs after agg1)
    ushort* h2 = (ushort*)bufB;                    // N*128 bf16 (overwrites hs after agg2)
    int* row_start = (int*)(bufB + (long long)N_NODES * HID);  // N+1
    float* dinv = (float*)(row_start + N_NODES + 1);  // N
    int* gcur = (int*)(dinv + N_NODES);            // NBUK
    int* gstart = gcur + NBUK;                     // N_GRAPHS+1
    int* csr = gstart + (N_GRAPHS + 1);            // E
    float* pooled = (float*)(csr + N_EDGES);       // G*HID

    // ----- CSR build -----
    hipMemsetAsync(gcur, 0, NBUK * sizeof(int), stream);
    hipMemsetAsync(pooled, 0, N_GRAPHS * HID * sizeof(float), stream);
    k_pass1<<<NBLK_P1, 1024, 0, stream>>>((const int4*)src, (const int4*)dst, gcur, bpak);
    k_pass2<<<NBUK, 1024, 0, stream>>>(gcur, bpak, x, batch, row_start, dinv, csr, xs, gstart);

    const int NGBLK = (N_NODES + 63) / 64;

    // ----- layer 1 -----
    k_agg1<<<N_NODES / 8, 256, 0, stream>>>(row_start, csr, (const uint32*)xs, dinv,
                                            (uint32*)agg1o);
    k_gemm_mfma<IN_DIM, 1><<<NGBLK, 256, 0, stream>>>(agg1o, W1, b1, dinv, hs);

    // ----- layer 2 -----
    k_agg2<<<N_NODES / 8, 256, 0, stream>>>(row_start, csr, (const uint2*)hs, dinv,
                                            (uint2*)agg2o);
    k_gemm_mfma<HID, 2><<<NGBLK, 256, 0, stream>>>(agg2o, W2, b2, dinv, h2);

    // ----- pool + head -----
    k_pool<<<N_GRAPHS * MAXCH, 256, 0, stream>>>((const uint32*)h2, gstart, pooled);
    k_head<<<1, 256, 0, stream>>>(pooled, gstart, Wfc, bfc, out);
}

// Round 16
// 208.398 us; speedup vs baseline: 1.5390x; 1.0185x over previous
//
#include <hip/hip_runtime.h>
#include <math.h>

#define N_NODES 100000
#define N_EDGES 1600000
#define IN_DIM 64
#define HID 128
#define OUT_DIM 2
#define N_GRAPHS 64

#define NBUK ((N_NODES + 255) / 256)         // 391 buckets of 256 nodes
#define BCAP 4608                            // slots per bucket (mean 4096, 8 sigma)
#define E4 (N_EDGES / 4)                     // 400000 int4 edge groups
#define NBLK_P1 ((E4 + 1023) / 1024)         // 391

typedef unsigned int uint32;
typedef __attribute__((ext_vector_type(8))) short bf16x8;
typedef __attribute__((ext_vector_type(4))) float f32x4;

static __device__ __forceinline__ ushort f2bf(float f) {
    uint32 u = __float_as_uint(f);
    uint32 r = (u + 0x7fff + ((u >> 16) & 1)) >> 16;  // RNE
    return (ushort)r;
}
static __device__ __forceinline__ float bf2f(uint32 u) {
    return __uint_as_float(u << 16);
}
static __device__ __forceinline__ float bflo(uint32 u) { return bf2f(u & 0xffffu); }
static __device__ __forceinline__ float bfhi(uint32 u) { return bf2f(u >> 16); }

// ---------------- bucketed CSR build ----------------
// gcur holds per-bucket COUNTS (memset 0). Edge packed: (dst&255)<<24 | src.
__global__ __launch_bounds__(1024) void k_pass1(const int4* __restrict__ src4,
                                                const int4* __restrict__ dst4,
                                                int* __restrict__ gcur,
                                                int* __restrict__ bpak) {
    __shared__ int hist[NBUK];
    __shared__ int base[NBUK];
    int tid = threadIdx.x;
    if (tid < NBUK) hist[tid] = 0;
    __syncthreads();
    int i4 = blockIdx.x * 1024 + tid;
    bool act = i4 < E4;
    int4 d = {0, 0, 0, 0}, s = {0, 0, 0, 0};
    if (act) {
        d = dst4[i4];
        s = src4[i4];
        atomicAdd(&hist[d.x >> 8], 1);
        atomicAdd(&hist[d.y >> 8], 1);
        atomicAdd(&hist[d.z >> 8], 1);
        atomicAdd(&hist[d.w >> 8], 1);
    }
    __syncthreads();
    if (tid < NBUK) {
        int c = hist[tid];
        base[tid] = tid * BCAP + (c ? atomicAdd(&gcur[tid], c) : 0);
        hist[tid] = 0;
    }
    __syncthreads();
    if (act) {
        int b0 = d.x >> 8, r0 = atomicAdd(&hist[b0], 1);
        int b1 = d.y >> 8, r1 = atomicAdd(&hist[b1], 1);
        int b2 = d.z >> 8, r2 = atomicAdd(&hist[b2], 1);
        int b3 = d.w >> 8, r3 = atomicAdd(&hist[b3], 1);
        bpak[base[b0] + r0] = ((d.x & 255) << 24) | s.x;
        bpak[base[b1] + r1] = ((d.y & 255) << 24) | s.y;
        bpak[base[b2] + r2] = ((d.z & 255) << 24) | s.z;
        bpak[base[b3] + r3] = ((d.w & 255) << 24) | s.w;
    }
}

// pass 2: per-bucket counting sort + fused xscale + fused graph-boundary detection.
__global__ __launch_bounds__(1024) void k_pass2(const int* __restrict__ gcur,
                                                const int* __restrict__ bpak,
                                                const float* __restrict__ x,
                                                const int* __restrict__ batch,
                                                int* __restrict__ row_start,
                                                float* __restrict__ dinv,
                                                int* __restrict__ csr,
                                                ushort* __restrict__ xs,
                                                int* __restrict__ gstart) {
    __shared__ int cnt[256];
    __shared__ int sc[256];
    __shared__ int lst[256];
    __shared__ float sdinv[256];
    __shared__ int sg[1024];
    __shared__ int sgb;
    int b = blockIdx.x;
    int tid = threadIdx.x;
    int node0 = b * 256;
    int nloc = N_NODES - node0;
    if (nloc > 256) nloc = 256;
    int bbase = b * BCAP;
    int Eb = gcur[b];

    // exclusive prefix over bucket counts -> global base gb
    sg[tid] = (tid < NBUK) ? gcur[tid] : 0;
    if (tid < 256) cnt[tid] = 0;
    __syncthreads();
    for (int off = 1; off < 512; off <<= 1) {
        int u = (tid >= off) ? sg[tid - off] : 0;
        __syncthreads();
        sg[tid] += u;
        __syncthreads();
    }
    if (tid == 0) sgb = (b == 0) ? 0 : sg[b - 1];
    __syncthreads();
    int gb = sgb;

    for (int i = tid; i < Eb; i += 1024) atomicAdd(&cnt[(uint32)bpak[bbase + i] >> 24], 1);
    __syncthreads();
    int v = 0;
    if (tid < 256) {
        v = cnt[tid];
        sc[tid] = v;
    }
    __syncthreads();
    for (int off = 1; off < 256; off <<= 1) {
        int u = 0;
        if (tid < 256 && tid >= off) u = sc[tid - off];
        __syncthreads();
        if (tid < 256) sc[tid] += u;
        __syncthreads();
    }
    if (tid < 256) {
        int excl = sc[tid] - v;
        lst[tid] = excl;
        if (tid < nloc) {
            int n = node0 + tid;
            float dv = rsqrtf((float)(v + 1));  // +1 self loop
            row_start[n] = gb + excl;
            dinv[n] = dv;
            sdinv[tid] = dv;
            // fused graph-boundary detection (batch sorted)
            if (n == 0) {
                for (int g = 0; g <= batch[0]; ++g) gstart[g] = 0;
            } else {
                int a = batch[n - 1], bb = batch[n];
                for (int g = a + 1; g <= bb; ++g) gstart[g] = n;
            }
            if (n == N_NODES - 1) {
                for (int g = batch[n] + 1; g <= N_GRAPHS; ++g) gstart[g] = N_NODES;
                row_start[N_NODES] = N_EDGES;
            }
        }
        cnt[tid] = 0;
    }
    __syncthreads();
    for (int i = tid; i < Eb; i += 1024) {
        int p = bpak[bbase + i];
        int dl = (uint32)p >> 24;
        int r = atomicAdd(&cnt[dl], 1);
        csr[gb + lst[dl] + r] = p & 0xFFFFFF;
    }
    // fused xscale for this block's 256 nodes
    int f0 = node0 * 16;
    int f1 = (node0 + nloc) * 16;
    for (int idx = f0 + tid; idx < f1; idx += 1024) {
        float dv = sdinv[(idx >> 4) - node0];
        float4 vv = ((const float4*)x)[idx];
        ushort4 o;
        o.x = f2bf(vv.x * dv);
        o.y = f2bf(vv.y * dv);
        o.z = f2bf(vv.z * dv);
        o.w = f2bf(vv.w * dv);
        ((ushort4*)xs)[idx] = o;
    }
}

// ---------------- aggregation (gather, CSR, bf16 in AND out, 8-deep MLP) ----------------
__global__ __launch_bounds__(256) void k_agg1(const int* __restrict__ row_start,
                                              const int* __restrict__ csr,
                                              const uint32* __restrict__ xs,
                                              const float* __restrict__ dinv,
                                              uint32* __restrict__ outb) {
    int d = blockIdx.x * 8 + (threadIdx.x >> 5);
    int l = threadIdx.x & 31;
    float dd = dinv[d];
    uint32 u = xs[(long long)d * 32 + l];
    float a0 = bflo(u), a1 = bfhi(u);
    int e = row_start[d];
    int eend = row_start[d + 1];
    for (; e + 7 < eend; e += 8) {
        int s0 = csr[e], s1 = csr[e + 1], s2 = csr[e + 2], s3 = csr[e + 3];
        int s4 = csr[e + 4], s5 = csr[e + 5], s6 = csr[e + 6], s7 = csr[e + 7];
        uint32 w0 = xs[(long long)s0 * 32 + l];
        uint32 w1 = xs[(long long)s1 * 32 + l];
        uint32 w2 = xs[(long long)s2 * 32 + l];
        uint32 w3 = xs[(long long)s3 * 32 + l];
        uint32 w4 = xs[(long long)s4 * 32 + l];
        uint32 w5 = xs[(long long)s5 * 32 + l];
        uint32 w6 = xs[(long long)s6 * 32 + l];
        uint32 w7 = xs[(long long)s7 * 32 + l];
        a0 += ((bflo(w0) + bflo(w1)) + (bflo(w2) + bflo(w3))) +
              ((bflo(w4) + bflo(w5)) + (bflo(w6) + bflo(w7)));
        a1 += ((bfhi(w0) + bfhi(w1)) + (bfhi(w2) + bfhi(w3))) +
              ((bfhi(w4) + bfhi(w5)) + (bfhi(w6) + bfhi(w7)));
    }
    for (; e + 3 < eend; e += 4) {
        int s0 = csr[e], s1 = csr[e + 1], s2 = csr[e + 2], s3 = csr[e + 3];
        uint32 w0 = xs[(long long)s0 * 32 + l];
        uint32 w1 = xs[(long long)s1 * 32 + l];
        uint32 w2 = xs[(long long)s2 * 32 + l];
        uint32 w3 = xs[(long long)s3 * 32 + l];
        a0 += (bflo(w0) + bflo(w1)) + (bflo(w2) + bflo(w3));
        a1 += (bfhi(w0) + bfhi(w1)) + (bfhi(w2) + bfhi(w3));
    }
    for (; e < eend; ++e) {
        uint32 w = xs[(long long)csr[e] * 32 + l];
        a0 += bflo(w);
        a1 += bfhi(w);
    }
    outb[(long long)d * 32 + l] = (uint32)f2bf(a0 * dd) | ((uint32)f2bf(a1 * dd) << 16);
}

__global__ __launch_bounds__(256) void k_agg2(const int* __restrict__ row_start,
                                              const int* __restrict__ csr,
                                              const uint2* __restrict__ hs,
                                              const float* __restrict__ dinv,
                                              uint2* __restrict__ outb) {
    int d = blockIdx.x * 8 + (threadIdx.x >> 5);
    int l = threadIdx.x & 31;
    float dd = dinv[d];
    uint2 u = hs[(long long)d * 32 + l];
    float a0 = bflo(u.x), a1 = bfhi(u.x), a2 = bflo(u.y), a3 = bfhi(u.y);
    int e = row_start[d];
    int eend = row_start[d + 1];
    for (; e + 7 < eend; e += 8) {
        int s0 = csr[e], s1 = csr[e + 1], s2 = csr[e + 2], s3 = csr[e + 3];
        int s4 = csr[e + 4], s5 = csr[e + 5], s6 = csr[e + 6], s7 = csr[e + 7];
        uint2 w0 = hs[(long long)s0 * 32 + l];
        uint2 w1 = hs[(long long)s1 * 32 + l];
        uint2 w2 = hs[(long long)s2 * 32 + l];
        uint2 w3 = hs[(long long)s3 * 32 + l];
        uint2 w4 = hs[(long long)s4 * 32 + l];
        uint2 w5 = hs[(long long)s5 * 32 + l];
        uint2 w6 = hs[(long long)s6 * 32 + l];
        uint2 w7 = hs[(long long)s7 * 32 + l];
        a0 += ((bflo(w0.x) + bflo(w1.x)) + (bflo(w2.x) + bflo(w3.x))) +
              ((bflo(w4.x) + bflo(w5.x)) + (bflo(w6.x) + bflo(w7.x)));
        a1 += ((bfhi(w0.x) + bfhi(w1.x)) + (bfhi(w2.x) + bfhi(w3.x))) +
              ((bfhi(w4.x) + bfhi(w5.x)) + (bfhi(w6.x) + bfhi(w7.x)));
        a2 += ((bflo(w0.y) + bflo(w1.y)) + (bflo(w2.y) + bflo(w3.y))) +
              ((bflo(w4.y) + bflo(w5.y)) + (bflo(w6.y) + bflo(w7.y)));
        a3 += ((bfhi(w0.y) + bfhi(w1.y)) + (bfhi(w2.y) + bfhi(w3.y))) +
              ((bfhi(w4.y) + bfhi(w5.y)) + (bfhi(w6.y) + bfhi(w7.y)));
    }
    for (; e + 3 < eend; e += 4) {
        int s0 = csr[e], s1 = csr[e + 1], s2 = csr[e + 2], s3 = csr[e + 3];
        uint2 w0 = hs[(long long)s0 * 32 + l];
        uint2 w1 = hs[(long long)s1 * 32 + l];
        uint2 w2 = hs[(long long)s2 * 32 + l];
        uint2 w3 = hs[(long long)s3 * 32 + l];
        a0 += (bflo(w0.x) + bflo(w1.x)) + (bflo(w2.x) + bflo(w3.x));
        a1 += (bfhi(w0.x) + bfhi(w1.x)) + (bfhi(w2.x) + bfhi(w3.x));
        a2 += (bflo(w0.y) + bflo(w1.y)) + (bflo(w2.y) + bflo(w3.y));
        a3 += (bfhi(w0.y) + bfhi(w1.y)) + (bfhi(w2.y) + bfhi(w3.y));
    }
    for (; e < eend; ++e) {
        uint2 w = hs[(long long)csr[e] * 32 + l];
        a0 += bflo(w.x);
        a1 += bfhi(w.x);
        a2 += bflo(w.y);
        a3 += bfhi(w.y);
    }
    uint2 o;
    o.x = (uint32)f2bf(a0 * dd) | ((uint32)f2bf(a1 * dd) << 16);
    o.y = (uint32)f2bf(a2 * dd) | ((uint32)f2bf(a3 * dd) << 16);
    outb[(long long)d * 32 + l] = o;
}

// ---------------- MFMA GEMM: relu(A[N,K](bf16) @ W[K,128] + b) ----------------
// OUTM 1: store bf16(v*dinv[row]) to outb.
// OUTM 3: no store; fused mean-pool numerator -> atomicAdd into pooled[g*128+col].
template <int K, int OUTM>
__global__ __launch_bounds__(256) void k_gemm_mfma(const ushort* __restrict__ A,
                                                   const float* __restrict__ W,
                                                   const float* __restrict__ bias,
                                                   const float* __restrict__ dinv,
                                                   ushort* __restrict__ outb,
                                                   const int* __restrict__ batch,
                                                   float* __restrict__ pooled) {
    constexpr int KSTEPS = K / 32;
    constexpr int LDSK = K + 8;          // pad: col stride 4 banks -> 2-way (free)
    __shared__ ushort WT[128 * LDSK];    // [col][k] bf16
    __shared__ float pcA[128];
    __shared__ float pcB[128];
    int tid = threadIdx.x;
    for (int idx = tid; idx < K * 128; idx += 256) {
        int k = idx >> 7, c = idx & 127;
        WT[c * LDSK + k] = f2bf(W[idx]);
    }
    if (OUTM == 3 && tid < 128) {
        pcA[tid] = 0.f;
        pcB[tid] = 0.f;
    }
    __syncthreads();

    int w = tid >> 6, l = tid & 63;
    int row0 = blockIdx.x * 64 + w * 16;
    int arow = row0 + (l & 15);
    if (arow > N_NODES - 1) arow = N_NODES - 1;
    int koff = (l >> 4) * 8;

    bf16x8 af[KSTEPS];
#pragma unroll
    for (int ks = 0; ks < KSTEPS; ++ks)
        af[ks] = *(const bf16x8*)(A + (long long)arow * K + ks * 32 + koff);

    f32x4 acc[8];
#pragma unroll
    for (int t = 0; t < 8; ++t) acc[t] = (f32x4){0.f, 0.f, 0.f, 0.f};

#pragma unroll
    for (int ks = 0; ks < KSTEPS; ++ks) {
#pragma unroll
        for (int t = 0; t < 8; ++t) {
            int c = t * 16 + (l & 15);
            bf16x8 bf = *(const bf16x8*)&WT[c * LDSK + ks * 32 + koff];
            acc[t] = __builtin_amdgcn_mfma_f32_16x16x32_bf16(af[ks], bf, acc[t], 0, 0, 0);
        }
    }

    int rbase = row0 + ((l >> 4) << 2);
    if (OUTM == 1) {
#pragma unroll
        for (int t = 0; t < 8; ++t) {
            int col = t * 16 + (l & 15);
            float bb = bias[col];
#pragma unroll
            for (int i = 0; i < 4; ++i) {
                int row = rbase + i;
                if (row < N_NODES) {
                    float v = acc[t][i] + bb;
                    v = v > 0.f ? v : 0.f;
                    outb[(long long)row * HID + col] = f2bf(v * dinv[row]);
                }
            }
        }
    } else {
        // fused pool: block covers rows [blk0, blk0+64) spanning <=2 graphs
        int blk0 = blockIdx.x * 64;
        int lastrow = blk0 + 63;
        if (lastrow > N_NODES - 1) lastrow = N_NODES - 1;
        int g0 = batch[blk0];
        int g1 = batch[lastrow];
        bool twoseg = (g1 != g0);
        int bg[4];
#pragma unroll
        for (int i = 0; i < 4; ++i) {
            int row = rbase + i;
            bg[i] = (row < N_NODES) ? batch[row] : -1;
        }
#pragma unroll
        for (int t = 0; t < 8; ++t) {
            int col = t * 16 + (l & 15);
            float bb = bias[col];
            float sA = 0.f, sB = 0.f;
#pragma unroll
            for (int i = 0; i < 4; ++i) {
                if (bg[i] >= 0) {
                    float v = acc[t][i] + bb;
                    v = v > 0.f ? v : 0.f;
                    if (bg[i] == g0) sA += v;
                    else sB += v;
                }
            }
            atomicAdd(&pcA[col], sA);
            if (twoseg) atomicAdd(&pcB[col], sB);
        }
        __syncthreads();
        if (tid < 128) {
            atomicAdd(&pooled[g0 * HID + tid], pcA[tid]);
            if (twoseg) atomicAdd(&pooled[g1 * HID + tid], pcB[tid]);
        }
    }
}

// ---------------- head: 4 lanes per graph ----------------
__global__ __launch_bounds__(256) void k_head(const float* __restrict__ pooled,
                                              const int* __restrict__ gstart,
                                              const float* __restrict__ Wfc,
                                              const float* __restrict__ bfc,
                                              float* __restrict__ out) {
    int t = threadIdx.x;
    int g = t >> 2, sub = t & 3;
    float inv = 1.0f / fmaxf((float)(gstart[g + 1] - gstart[g]), 1.0f);
    float l0 = 0.f, l1 = 0.f;
    for (int j = sub * 32; j < sub * 32 + 32; ++j) {
        float p = pooled[g * HID + j] * inv;
        l0 += p * Wfc[j * OUT_DIM + 0];
        l1 += p * Wfc[j * OUT_DIM + 1];
    }
    l0 += __shfl_xor(l0, 1);
    l1 += __shfl_xor(l1, 1);
    l0 += __shfl_xor(l0, 2);
    l1 += __shfl_xor(l1, 2);
    if (sub == 0) {
        l0 += bfc[0];
        l1 += bfc[1];
        float m = fmaxf(l0, l1);
        float lse = m + logf(expf(l0 - m) + expf(l1 - m));
        out[g * OUT_DIM + 0] = l0 - lse;
        out[g * OUT_DIM + 1] = l1 - lse;
    }
}

extern "C" void kernel_launch(void* const* d_in, const int* in_sizes, int n_in,
                              void* d_out, int out_size, void* d_ws, size_t ws_size,
                              hipStream_t stream) {
    const float* x   = (const float*)d_in[0];
    const float* W1  = (const float*)d_in[1];
    const float* b1  = (const float*)d_in[2];
    const float* W2  = (const float*)d_in[3];
    const float* b2  = (const float*)d_in[4];
    const float* Wfc = (const float*)d_in[5];
    const float* bfc = (const float*)d_in[6];
    const int* ei    = (const int*)d_in[7];   // [2, E]
    const int* batch = (const int*)d_in[8];
    const int* src = ei;
    const int* dst = ei + N_EDGES;
    float* out = (float*)d_out;

    // workspace layout
    float* bufA = (float*)d_ws;                    // bpak overlay, then agg outputs (bf16)
    float* bufB = bufA + (long long)N_NODES * HID; // xs / hs (bf16)
    int* bpak = (int*)bufA;                        // NBUK*BCAP packed edges (dead before agg1)
    ushort* agg1o = (ushort*)bufA;                 // N*64 bf16
    ushort* agg2o = (ushort*)bufA;                 // N*128 bf16
    ushort* xs = (ushort*)bufB;                    // N*64 bf16
    ushort* hs = (ushort*)bufB;                    // N*128 bf16 (overwrites xs after agg1)
    int* row_start = (int*)(bufB + (long long)N_NODES * HID);  // N+1
    float* dinv = (float*)(row_start + N_NODES + 1);  // N
    int* gcur = (int*)(dinv + N_NODES);            // NBUK
    int* gstart = gcur + NBUK;                     // N_GRAPHS+1
    int* csr = gstart + (N_GRAPHS + 1);            // E
    float* pooled = (float*)(csr + N_EDGES);       // G*HID

    // ----- CSR build -----
    hipMemsetAsync(gcur, 0, NBUK * sizeof(int), stream);
    hipMemsetAsync(pooled, 0, N_GRAPHS * HID * sizeof(float), stream);
    k_pass1<<<NBLK_P1, 1024, 0, stream>>>((const int4*)src, (const int4*)dst, gcur, bpak);
    k_pass2<<<NBUK, 1024, 0, stream>>>(gcur, bpak, x, batch, row_start, dinv, csr, xs, gstart);

    const int NGBLK = (N_NODES + 63) / 64;

    // ----- layer 1 -----
    k_agg1<<<N_NODES / 8, 256, 0, stream>>>(row_start, csr, (const uint32*)xs, dinv,
                                            (uint32*)agg1o);
    k_gemm_mfma<IN_DIM, 1><<<NGBLK, 256, 0, stream>>>(agg1o, W1, b1, dinv, hs, nullptr,
                                                      nullptr);

    // ----- layer 2 (GEMM with fused mean-pool numerator) -----
    k_agg2<<<N_NODES / 8, 256, 0, stream>>>(row_start, csr, (const uint2*)hs, dinv,
                                            (uint2*)agg2o);
    k_gemm_mfma<HID, 3><<<NGBLK, 256, 0, stream>>>(agg2o, W2, b2, dinv, nullptr, batch,
                                                   pooled);

    // ----- head -----
    k_head<<<1, 256, 0, stream>>>(pooled, gstart, Wfc, bfc, out);
}